// Round 3
// baseline (115.085 us; speedup 1.0000x reference)
//
#include <hip/hip_runtime.h>

#define IMG_H 200
#define IMG_W 200
#define VOLD  256          // volume is 256^3, strides: x<<16, y<<8, z
#define KPH   16           // threads (phases) per pixel

// 8-byte load expressed as a true 8B access with only 4B alignment guarantee.
// gfx950 runs with unaligned-access-mode enabled -> emits global_load_dwordx2.
__device__ __forceinline__ float2 ld2(const float* __restrict__ p) {
    float2 r;
    __builtin_memcpy(&r, p, sizeof(float2));
    return r;
}

__global__ __launch_bounds__(256) void drr_kernel(
    const float* __restrict__ vol,
    const float* __restrict__ kinv,   // [3][3]
    const float* __restrict__ rt,     // [4][4]
    const float* __restrict__ sddp,   // [1]
    const float* __restrict__ aff,    // [4][4]
    const int*   __restrict__ nsp,    // [1]
    float*       __restrict__ out)    // [H*W]
{
    const int tid   = blockIdx.x * blockDim.x + threadIdx.x;
    const int p     = tid / KPH;      // pixel index
    const int phase = tid & (KPH - 1);
    if (p >= IMG_H * IMG_W) return;

    const int   N     = nsp[0];
    const float sdd   = sddp[0];
    const float invN1 = 1.0f / (float)(N - 1);

    const float u = (float)(p % IMG_W);
    const float v = (float)(p / IMG_W);

    // tgt_cam = K^-1 * (u,v,1) * sdd
    const float tcx = (kinv[0]*u + kinv[1]*v + kinv[2]) * sdd;
    const float tcy = (kinv[3]*u + kinv[4]*v + kinv[5]) * sdd;
    const float tcz = (kinv[6]*u + kinv[7]*v + kinv[8]) * sdd;

    // ray = R * tgt_cam ; src = t
    const float rx = rt[0]*tcx + rt[1]*tcy + rt[2]*tcz;
    const float ry = rt[4]*tcx + rt[5]*tcy + rt[6]*tcz;
    const float rz = rt[8]*tcx + rt[9]*tcy + rt[10]*tcz;
    const float sx = rt[3], sy = rt[7], sz = rt[11];

    // voxel-space: vox(t) = base + t * dir
    const float bx = aff[0]*sx + aff[1]*sy + aff[2]*sz  + aff[3];
    const float by = aff[4]*sx + aff[5]*sy + aff[6]*sz  + aff[7];
    const float bz = aff[8]*sx + aff[9]*sy + aff[10]*sz + aff[11];
    const float dx = aff[0]*rx + aff[1]*ry + aff[2]*rz;
    const float dy = aff[4]*rx + aff[5]*ry + aff[6]*rz;
    const float dz = aff[8]*rx + aff[9]*ry + aff[10]*rz;

    // ---- culling: sample contributes only if all coords in (-1, 256);
    // ---- interior (uncheckable-fast) requires all coords in [0, 255).
    float t0 = 0.0f, t1 = 1.0f;      // any-contribution interval
    float ti0 = 0.0f, ti1 = 1.0f;    // fully-interior interval
    {
        const float bs[3] = {bx, by, bz};
        const float ds[3] = {dx, dy, dz};
        #pragma unroll
        for (int d = 0; d < 3; ++d) {
            const float b  = bs[d];
            const float dd = ds[d];
            if (fabsf(dd) > 1e-20f) {
                const float inv = 1.0f / dd;
                const float ta = (-1.0f  - b) * inv;
                const float tb = (256.0f - b) * inv;
                t0 = fmaxf(t0, fminf(ta, tb));
                t1 = fminf(t1, fmaxf(ta, tb));
                const float tc = (0.0f   - b) * inv;
                const float td = (254.999f - b) * inv;
                ti0 = fmaxf(ti0, fminf(tc, td));
                ti1 = fminf(ti1, fmaxf(tc, td));
            } else {
                if (b <= -1.0f || b >= 256.0f) { t0 = 1.0f; t1 = -1.0f; }
                if (b < 0.0f || b >= 254.999f) { ti0 = 1.0f; ti1 = -1.0f; }
            }
        }
    }
    const float fN1 = (float)(N - 1);
    int s_lo = 0, s_hi = -1;
    if (t0 <= t1) {
        s_lo = max((int)floorf(t0 * fN1) - 1, 0);
        s_hi = min((int)ceilf (t1 * fN1) + 1, N - 1);
    }
    // conservatively-interior sample sub-range
    int i_lo = s_hi + 1, i_hi = s_hi;   // empty by default
    if (ti0 <= ti1) {
        i_lo = max((int)ceilf (ti0 * fN1) + 1, s_lo);
        i_hi = min((int)floorf(ti1 * fN1) - 1, s_hi);
    }

    float acc = 0.0f;

    // ---- interior fast loop: no bounds checks, float2 corner loads
    #pragma unroll 2
    for (int s = i_lo + phase; s <= i_hi; s += KPH) {
        const float t = (float)s * invN1;
        const float x = fmaf(t, dx, bx);
        const float y = fmaf(t, dy, by);
        const float z = fmaf(t, dz, bz);
        const float fx = floorf(x), fy = floorf(y), fz = floorf(z);
        const int ix = (int)fx, iy = (int)fy, iz = (int)fz;
        const float wx = x - fx, wy = y - fy, wz = z - fz;

        const float* pb = vol + ((ix << 16) + (iy << 8) + iz);
        const float2 q00 = ld2(pb);                 // c000, c001
        const float2 q01 = ld2(pb + 256);           // c010, c011
        const float2 q10 = ld2(pb + 65536);         // c100, c101
        const float2 q11 = ld2(pb + 65536 + 256);   // c110, c111

        const float c00 = fmaf(wz, q00.y - q00.x, q00.x);
        const float c01 = fmaf(wz, q01.y - q01.x, q01.x);
        const float c10 = fmaf(wz, q10.y - q10.x, q10.x);
        const float c11 = fmaf(wz, q11.y - q11.x, q11.x);
        const float c0  = fmaf(wy, c01 - c00, c00);
        const float c1  = fmaf(wy, c11 - c10, c10);
        acc += fmaf(wx, c1 - c0, c0);
    }

    // ---- edge samples (checked path): s in [s_lo, i_lo) and (i_hi, s_hi]
    for (int seg = 0; seg < 2; ++seg) {
        const int lo = seg ? (i_hi + 1) : s_lo;
        const int hi = seg ? s_hi       : (i_lo - 1);
        for (int s = lo + phase; s <= hi; s += KPH) {
            const float t = (float)s * invN1;
            const float x = fmaf(t, dx, bx);
            const float y = fmaf(t, dy, by);
            const float z = fmaf(t, dz, bz);
            const float fx = floorf(x), fy = floorf(y), fz = floorf(z);
            const int ix = (int)fx, iy = (int)fy, iz = (int)fz;
            const float wx = x - fx, wy = y - fy, wz = z - fz;

            const bool x0 = (unsigned)ix       < 256u;
            const bool x1 = (unsigned)(ix + 1) < 256u;
            const bool y0 = (unsigned)iy       < 256u;
            const bool y1 = (unsigned)(iy + 1) < 256u;
            const bool z0 = (unsigned)iz       < 256u;
            const bool z1 = (unsigned)(iz + 1) < 256u;
            const int bx0 = ix << 16, bx1 = (ix + 1) << 16;
            const int by0 = iy << 8,  by1 = (iy + 1) << 8;
            const float c000 = (x0 && y0 && z0) ? vol[bx0 + by0 + iz]     : 0.0f;
            const float c001 = (x0 && y0 && z1) ? vol[bx0 + by0 + iz + 1] : 0.0f;
            const float c010 = (x0 && y1 && z0) ? vol[bx0 + by1 + iz]     : 0.0f;
            const float c011 = (x0 && y1 && z1) ? vol[bx0 + by1 + iz + 1] : 0.0f;
            const float c100 = (x1 && y0 && z0) ? vol[bx1 + by0 + iz]     : 0.0f;
            const float c101 = (x1 && y0 && z1) ? vol[bx1 + by0 + iz + 1] : 0.0f;
            const float c110 = (x1 && y1 && z0) ? vol[bx1 + by1 + iz]     : 0.0f;
            const float c111 = (x1 && y1 && z1) ? vol[bx1 + by1 + iz + 1] : 0.0f;

            const float c00 = fmaf(wz, c001 - c000, c000);
            const float c01 = fmaf(wz, c011 - c010, c010);
            const float c10 = fmaf(wz, c101 - c100, c100);
            const float c11 = fmaf(wz, c111 - c110, c110);
            const float c0  = fmaf(wy, c01 - c00, c00);
            const float c1  = fmaf(wy, c11 - c10, c10);
            acc += fmaf(wx, c1 - c0, c0);
        }
    }

    // reduce the 16 phases of this pixel (contiguous lanes)
    acc += __shfl_down(acc, 8, KPH);
    acc += __shfl_down(acc, 4, KPH);
    acc += __shfl_down(acc, 2, KPH);
    acc += __shfl_down(acc, 1, KPH);

    if (phase == 0) {
        const float step = sqrtf(rx*rx + ry*ry + rz*rz) * invN1;
        out[p] = acc * step;
    }
}

extern "C" void kernel_launch(void* const* d_in, const int* in_sizes, int n_in,
                              void* d_out, int out_size, void* d_ws, size_t ws_size,
                              hipStream_t stream) {
    const float* vol  = (const float*)d_in[0];
    const float* kinv = (const float*)d_in[1];
    const float* rt   = (const float*)d_in[2];
    const float* sdd  = (const float*)d_in[3];
    const float* aff  = (const float*)d_in[4];
    const int*   nsp  = (const int*)d_in[5];
    float* out = (float*)d_out;

    const long long threads = (long long)IMG_H * IMG_W * KPH;   // 640000
    dim3 block(256);
    dim3 grid((unsigned)((threads + 255) / 256));               // 2500
    drr_kernel<<<grid, block, 0, stream>>>(vol, kinv, rt, sdd, aff, nsp, out);
}